// Round 18
// baseline (688.201 us; speedup 1.0000x reference)
//
#include <hip/hip_runtime.h>

// SAModule (PointNet++): FPS -> kNN(32) -> [x||rel] MLP(67->128->128->256) -> max over K.
// B=16, N=4096, C=64, M=1024, K=32.
// R17 = R14 + two FPS latency levers (R16's op_sel lever dropped: VOP3P src1
// must be a 64-bit pair, lone VGPR is an invalid operand):
//  (2) 4-candidate pp prefetch issued in parallel with the f64 fmax chain,
//      select via f64-equality cndmask (keys unique -> exact),
//  (3) publish duty (ipub + pos_s) rotated across waves by i&3 (wave 0 was
//      always last to the barrier; skew now ~1/4).

#define B_    16
#define N_    4096
#define M_    1024
#define AST   136
#define NWORK 240
#define NITEM (255 * 16)   // worker items, mset-major: it = mset*16 + b

typedef __bf16 bf16x8 __attribute__((ext_vector_type(8)));
typedef __bf16 bf16x4 __attribute__((ext_vector_type(4)));
typedef float  f32x4  __attribute__((ext_vector_type(4)));
typedef float  f32x2  __attribute__((ext_vector_type(2)));

// ---------------------------------------------------------------------------
// Weight prep: transpose + cast to bf16, pad W1 K-dim 67->96 with zeros.
// ---------------------------------------------------------------------------
__global__ __launch_bounds__(256) void prep_weights(
    const float* __restrict__ W1, const float* __restrict__ W2,
    const float* __restrict__ W3,
    __bf16* __restrict__ w1t, __bf16* __restrict__ w2t, __bf16* __restrict__ w3t) {
  const int t = blockIdx.x * 256 + threadIdx.x;   // 0..32767
  if (t < 128 * 96) {
    const int n = t / 96, k = t % 96;
    w1t[t] = (k < 67) ? (__bf16)W1[k * 128 + n] : (__bf16)0.0f;
  }
  if (t < 128 * 128) {
    const int n = t >> 7, k = t & 127;
    w2t[t] = (__bf16)W2[k * 128 + n];
  }
  {
    const int n = t >> 7, k = t & 127;   // t < 256*128 always
    w3t[t] = (__bf16)W3[k * 256 + n];
  }
}

// ---------------------------------------------------------------------------
__device__ __forceinline__ f32x2 pk_sub(f32x2 a, f32x2 b) {
  f32x2 d;
  asm("v_pk_add_f32 %0, %1, %2 neg_lo:[0,1] neg_hi:[0,1]" : "=v"(d) : "v"(a), "v"(b));
  return d;
}
__device__ __forceinline__ f32x2 pk_mul(f32x2 a, f32x2 b) {
  f32x2 d;
  asm("v_pk_mul_f32 %0, %1, %2" : "=v"(d) : "v"(a), "v"(b));
  return d;
}
__device__ __forceinline__ f32x2 pk_add(f32x2 a, f32x2 b) {
  f32x2 d;
  asm("v_pk_add_f32 %0, %1, %2" : "=v"(d) : "v"(a), "v"(b));
  return d;
}

// argmax key as positive f64: hi = f32 bits of D (>=0, < 0x7FF00000), lo = ~idx.
// IEEE f64 ordering == u64 bit ordering for these patterns.
__device__ __forceinline__ double mk_key(float d, unsigned lo) {
  unsigned long long k = ((unsigned long long)__float_as_uint(d) << 32) | lo;
  return __builtin_bit_cast(double, k);
}
// hi-half (the f32 distance) of a key; lo-half is a per-slot constant.
__device__ __forceinline__ float kd_hi(double k) {
  return __int_as_float((int)(__builtin_bit_cast(unsigned long long, k) >> 32));
}
__device__ __forceinline__ double kd_set_hi(double k, float h) {
  unsigned long long u = __builtin_bit_cast(unsigned long long, k);
  u = (u & 0xFFFFFFFFull) | ((unsigned long long)__float_as_uint(h) << 32);
  return __builtin_bit_cast(double, u);
}
__device__ __forceinline__ int kd_idx(double k) {
  return (int)(~(unsigned)__builtin_bit_cast(unsigned long long, k));
}

template <int CTRL>
__device__ __forceinline__ double dpp_max_f64(double v) {
  unsigned long long k = __builtin_bit_cast(unsigned long long, v);
  unsigned lo = (unsigned)__builtin_amdgcn_update_dpp(0, (int)(unsigned)k,         CTRL, 0xF, 0xF, true);
  unsigned hi = (unsigned)__builtin_amdgcn_update_dpp(0, (int)(unsigned)(k >> 32), CTRL, 0xF, 0xF, true);
  double p = __builtin_bit_cast(double, ((unsigned long long)hi << 32) | lo);
  return fmax(v, p);   // 0-filled lanes give +0.0, which always loses (keys > 0)
}

union ShU {
  struct { float4 pp[N_]; unsigned long long sw[2][4]; } f;   // fps / knn view
  struct { __bf16 A[128 * AST]; __bf16 Bv[128 * AST]; } g;    // mlp view
  char force_cu_exclusive[84 * 1024];   // 2x84KB > 160KB -> 1 block/CU, HW-guaranteed
};

// ---------------------------------------------------------------------------
// kNN + gather + MLP + maxpool for one (b, mset) item. Requires sh.f.pp to
// hold cloud b as float4 and ci = this wave's centroid point index.
// ---------------------------------------------------------------------------
__device__ __forceinline__ void process_item(
    ShU& sh, int tid, int b, int mset, int ci,
    const float* __restrict__ x, const float* __restrict__ pos,
    const float* __restrict__ b1, const float* __restrict__ b2,
    const float* __restrict__ b3,
    const __bf16* __restrict__ w1t, const __bf16* __restrict__ w2t,
    const __bf16* __restrict__ w3t, float* __restrict__ out) {
  const int w    = tid >> 6;
  const int lane = tid & 63;
  const float4 c = sh.f.pp[ci];

  // ---- kNN pass A: distances + lane-min key ----
  float d2v[64];
  unsigned long long kmin = ~0ull;
#pragma unroll
  for (int t = 0; t < 64; t++) {
    const int j = t * 64 + lane;
    const float4 p = sh.f.pp[j];
    float dx = __fsub_rn(p.x, c.x);
    float dy = __fsub_rn(p.y, c.y);
    float dz = __fsub_rn(p.z, c.z);
    float d  = __fadd_rn(__fadd_rn(__fmul_rn(dx, dx), __fmul_rn(dy, dy)),
                         __fmul_rn(dz, dz));
    d2v[t] = d;
    const unsigned long long k64 =
        ((unsigned long long)__float_as_uint(d) << 32) | (unsigned int)j;
    if (k64 < kmin) kmin = k64;
  }

  // ---- bitonic sort of lane-min keys; seed top-32; threshold T0 ----
  unsigned long long sk = kmin;
#pragma unroll
  for (int size = 2; size <= 64; size <<= 1) {
#pragma unroll
    for (int stride = size >> 1; stride > 0; stride >>= 1) {
      const unsigned long long other = __shfl_xor(sk, stride);
      const bool up      = ((lane & size) == 0);
      const bool lowhalf = ((lane & stride) == 0);
      const bool takeMin = (up == lowhalf);
      const bool swp     = takeMin ? (other < sk) : (other > sk);
      if (swp) sk = other;
    }
  }
  const unsigned long long T0 = __shfl(sk, 31);
  const bool seeded = (kmin <= T0);

  unsigned long long rkey = (lane < 32) ? sk : ~0ull;
  unsigned long long wk   = T0;

  // ---- pass B: scan, skipping seeded keys ----
#pragma unroll
  for (int t = 0; t < 64; t++) {
    const int j = t * 64 + lane;
    const unsigned long long k64 =
        ((unsigned long long)__float_as_uint(d2v[t]) << 32) | (unsigned int)j;
    const bool skip = seeded && (k64 == kmin);
    unsigned long long mask = __ballot((k64 < wk) && !skip);
    if (mask) {
      while (mask) {
        const int src = __ffsll((unsigned long long)mask) - 1;
        mask &= mask - 1;
        const unsigned long long cand = __shfl(k64, src);
        const int pos_i = (int)__popcll(__ballot(rkey < cand));  // >=32 -> no-op
        const unsigned long long sh_ = __shfl_up(rkey, 1);
        if (lane < 32) {
          if (lane == pos_i)      rkey = cand;
          else if (lane > pos_i)  rkey = sh_;
        }
      }
      wk = __shfl(rkey, 31);
    }
  }
  const int njl = (int)(rkey & 0xFFFFull);   // valid in lanes 0..31
  __syncthreads();   // all pp reads done before mlp buffers alias it

  // ---- gather: wave w fills rows [32w,32w+32) for its centroid ----
  {
    const int rl   = lane >> 1;
    const int half = lane & 1;
    const int r    = w * 32 + rl;
    const int nj   = __shfl(njl, rl);
    const float4* xr = (const float4*)(x + ((size_t)(b * N_ + nj)) * 64 + half * 32);
    __bf16* dst = &sh.g.A[r * AST + half * 32];
#pragma unroll
    for (int t = 0; t < 8; t++) {
      float4 v = xr[t];
      bf16x4 u;
      u[0] = (__bf16)v.x; u[1] = (__bf16)v.y; u[2] = (__bf16)v.z; u[3] = (__bf16)v.w;
      *(bf16x4*)(dst + t * 4) = u;
    }
    bf16x8 z;
#pragma unroll
    for (int q2 = 0; q2 < 8; q2++) z[q2] = (__bf16)0.0f;
    if (half == 0) {
      const float* pj = pos + ((size_t)(b * N_ + nj)) * 3;
      bf16x8 u = z;
      u[0] = (__bf16)(pj[0] - c.x);
      u[1] = (__bf16)(pj[1] - c.y);
      u[2] = (__bf16)(pj[2] - c.z);
      *(bf16x8*)&sh.g.A[r * AST + 64] = u;
      *(bf16x8*)&sh.g.A[r * AST + 72] = z;
    } else {
      *(bf16x8*)&sh.g.A[r * AST + 80] = z;
      *(bf16x8*)&sh.g.A[r * AST + 88] = z;
    }
  }
  __syncthreads();

  const int lrow = lane & 15;
  const int lk8  = (lane >> 4) << 3;
  const int orow = (lane >> 4) << 2;

  // ---- L1: msg(96) @ W1 -> relu -> Bv. Wave w: cols [32w,32w+32) ----
  {
    f32x4 acc[8][2];
#pragma unroll
    for (int n = 0; n < 2; n++) {
      const float bv = b1[(2 * w + n) * 16 + lrow];
      f32x4 a = {bv, bv, bv, bv};
#pragma unroll
      for (int rt = 0; rt < 8; rt++) acc[rt][n] = a;
    }
#pragma unroll
    for (int s = 0; s < 3; s++) {
      bf16x8 a[8];
#pragma unroll
      for (int rt = 0; rt < 8; rt++)
        a[rt] = *(const bf16x8*)&sh.g.A[(rt * 16 + lrow) * AST + s * 32 + lk8];
#pragma unroll
      for (int n = 0; n < 2; n++) {
        bf16x8 bb = *(const bf16x8*)&w1t[((2 * w + n) * 16 + lrow) * 96 + s * 32 + lk8];
#pragma unroll
        for (int rt = 0; rt < 8; rt++)
          acc[rt][n] = __builtin_amdgcn_mfma_f32_16x16x32_bf16(a[rt], bb, acc[rt][n], 0, 0, 0);
      }
    }
    __syncthreads();
#pragma unroll
    for (int n = 0; n < 2; n++)
#pragma unroll
      for (int rt = 0; rt < 8; rt++)
#pragma unroll
        for (int j = 0; j < 4; j++)
          sh.g.Bv[(rt * 16 + orow + j) * AST + (2 * w + n) * 16 + lrow] =
              (__bf16)fmaxf(acc[rt][n][j], 0.0f);
  }
  __syncthreads();

  // ---- L2: Bv(128) @ W2 -> relu -> A ----
  {
    f32x4 acc[8][2];
#pragma unroll
    for (int n = 0; n < 2; n++) {
      const float bv = b2[(2 * w + n) * 16 + lrow];
      f32x4 a = {bv, bv, bv, bv};
#pragma unroll
      for (int rt = 0; rt < 8; rt++) acc[rt][n] = a;
    }
#pragma unroll
    for (int s = 0; s < 4; s++) {
      bf16x8 a[8];
#pragma unroll
      for (int rt = 0; rt < 8; rt++)
        a[rt] = *(const bf16x8*)&sh.g.Bv[(rt * 16 + lrow) * AST + s * 32 + lk8];
#pragma unroll
      for (int n = 0; n < 2; n++) {
        bf16x8 bb = *(const bf16x8*)&w2t[((2 * w + n) * 16 + lrow) * 128 + s * 32 + lk8];
#pragma unroll
        for (int rt = 0; rt < 8; rt++)
          acc[rt][n] = __builtin_amdgcn_mfma_f32_16x16x32_bf16(a[rt], bb, acc[rt][n], 0, 0, 0);
      }
    }
    __syncthreads();
#pragma unroll
    for (int n = 0; n < 2; n++)
#pragma unroll
      for (int rt = 0; rt < 8; rt++)
#pragma unroll
        for (int j = 0; j < 4; j++)
          sh.g.A[(rt * 16 + orow + j) * AST + (2 * w + n) * 16 + lrow] =
              (__bf16)fmaxf(acc[rt][n][j], 0.0f);
  }
  __syncthreads();

  // ---- L3 + maxpool. Wave w: cols [64w,64w+64) in two passes ----
#pragma unroll
  for (int np = 0; np < 2; np++) {
    f32x4 acc[8][2];
#pragma unroll
    for (int n = 0; n < 2; n++) {
      const float bv = b3[(4 * w + 2 * np + n) * 16 + lrow];
      f32x4 a = {bv, bv, bv, bv};
#pragma unroll
      for (int rt = 0; rt < 8; rt++) acc[rt][n] = a;
    }
#pragma unroll
    for (int s = 0; s < 4; s++) {
      bf16x8 a[8];
#pragma unroll
      for (int rt = 0; rt < 8; rt++)
        a[rt] = *(const bf16x8*)&sh.g.A[(rt * 16 + lrow) * AST + s * 32 + lk8];
#pragma unroll
      for (int n = 0; n < 2; n++) {
        bf16x8 bb = *(const bf16x8*)&w3t[((4 * w + 2 * np + n) * 16 + lrow) * 128 + s * 32 + lk8];
#pragma unroll
        for (int rt = 0; rt < 8; rt++)
          acc[rt][n] = __builtin_amdgcn_mfma_f32_16x16x32_bf16(a[rt], bb, acc[rt][n], 0, 0, 0);
      }
    }
#pragma unroll
    for (int ccc = 0; ccc < 4; ccc++) {
#pragma unroll
      for (int n = 0; n < 2; n++) {
        f32x4 a0 = acc[2 * ccc][n], a1 = acc[2 * ccc + 1][n];
        float v = fmaxf(fmaxf(fmaxf(a0[0], a0[1]), fmaxf(a0[2], a0[3])),
                        fmaxf(fmaxf(a1[0], a1[1]), fmaxf(a1[2], a1[3])));
        v = fmaxf(v, __shfl_xor(v, 16));
        v = fmaxf(v, __shfl_xor(v, 32));
        v = fmaxf(v, 0.0f);
        if (lane < 16)
          out[((size_t)(b * M_ + mset * 4 + ccc)) * 256 + (4 * w + 2 * np + n) * 16 + lane] = v;
      }
    }
  }
}

// ---------------------------------------------------------------------------
__global__ __launch_bounds__(256) void fused_kernel(
    const float* __restrict__ pos, const float* __restrict__ x,
    const float* __restrict__ b1, const float* __restrict__ b2,
    const float* __restrict__ b3,
    const __bf16* __restrict__ w1t, const __bf16* __restrict__ w2t,
    const __bf16* __restrict__ w3t,
    int* __restrict__ ipub, int* __restrict__ ctr,
    float* __restrict__ out, float* __restrict__ pos_s) {
  __shared__ alignas(16) ShU sh;
  __shared__ int sh_item;
  const int tid = threadIdx.x;

  if (blockIdx.x < B_) {
    // ============ FPS producer (R14 body + levers 2/3) =======================
    __builtin_amdgcn_s_setprio(3);
    const int b = blockIdx.x;
    const float* pb = pos + (size_t)b * N_ * 3;
    for (int i = tid; i < N_; i += 256)
      sh.f.pp[i] = make_float4(pb[3 * i], pb[3 * i + 1], pb[3 * i + 2], 0.0f);
    __syncthreads();

    f32x2 X2[8], Y2[8], Z2[8];
    double KD[16];   // persistent keys: lo32 = ~idx (never changes), hi32 = f32bits(D)
    const unsigned ntid = ~(unsigned)tid;
#pragma unroll
    for (int j = 0; j < 8; j++) {
      float4 p0 = sh.f.pp[tid + ((2 * j) << 8)];
      float4 p1 = sh.f.pp[tid + ((2 * j + 1) << 8)];
      X2[j][0] = p0.x; X2[j][1] = p1.x;
      Y2[j][0] = p0.y; Y2[j][1] = p1.y;
      Z2[j][0] = p0.z; Z2[j][1] = p1.z;
      KD[2 * j]     = mk_key(1e30f, ntid - (unsigned)((2 * j) << 8));
      KD[2 * j + 1] = mk_key(1e30f, ntid - (unsigned)((2 * j + 1) << 8));
    }

    float4 q = sh.f.pp[0];
    if (tid == 0) {
      __hip_atomic_store(ipub + b * M_, 1, __ATOMIC_RELAXED,
                         __HIP_MEMORY_SCOPE_AGENT);   // idx 0, published as 0+1
      float* o = pos_s + (size_t)b * M_ * 3;
      o[0] = q.x; o[1] = q.y; o[2] = q.z;
    }

    int l0 = 0, l1 = 0, l2 = 0, l3 = 0;   // fps_idx[1020..1023]
    for (int i = 1; i < M_; i++) {
      f32x2 qx; qx[0] = q.x; qx[1] = q.x;
      f32x2 qy; qy[0] = q.y; qy[1] = q.y;
      f32x2 qz; qz[0] = q.z; qz[1] = q.z;
#pragma unroll
      for (int j = 0; j < 8; j++) {
        f32x2 dx = pk_sub(X2[j], qx);
        f32x2 dy = pk_sub(Y2[j], qy);
        f32x2 dz = pk_sub(Z2[j], qz);
        f32x2 t0 = pk_mul(dx, dx);
        f32x2 t1 = pk_mul(dy, dy);
        f32x2 s  = pk_add(t0, t1);
        f32x2 t2 = pk_mul(dz, dz);
        f32x2 d2 = pk_add(s, t2);
        // in-place hi-half update: v_min_f32 on the pair's hi reg, no packing
        KD[2 * j]     = kd_set_hi(KD[2 * j],     fminf(kd_hi(KD[2 * j]),     d2[0]));
        KD[2 * j + 1] = kd_set_hi(KD[2 * j + 1], fminf(kd_hi(KD[2 * j + 1]), d2[1]));
      }
      // tree reduce, level 1 non-destructive (KD persists across iterations)
      double t[8];
#pragma unroll
      for (int k = 0; k < 8; k++) t[k] = fmax(KD[k], KD[k + 8]);
#pragma unroll
      for (int s = 4; s > 0; s >>= 1)
#pragma unroll
        for (int k = 0; k < s; k++) t[k] = fmax(t[k], t[k + s]);
      double kk = t[0];

      // full-wave VALU-pipe reduce: lane 63 ends with the wave max
      kk = dpp_max_f64<0xB1>(kk);    // quad_perm xor1
      kk = dpp_max_f64<0x4E>(kk);    // quad_perm xor2
      kk = dpp_max_f64<0x141>(kk);   // row_half_mirror (xor4)
      kk = dpp_max_f64<0x140>(kk);   // row_mirror (xor8)
      kk = dpp_max_f64<0x142>(kk);   // row_bcast15
      kk = dpp_max_f64<0x143>(kk);   // row_bcast31

      const int par = i & 1;
      if ((tid & 63) == 63)
        sh.f.sw[par][tid >> 6] = __builtin_bit_cast(unsigned long long, kk);
      // LDS-only fence + raw barrier (global stores stay fire-and-forget)
      asm volatile("s_waitcnt lgkmcnt(0)" ::: "memory");
      __builtin_amdgcn_s_barrier();

      // prefetch all 4 candidates in parallel with the f64 fmax chain
      const double2 w01 = *(const double2*)&sh.f.sw[par][0];
      const double2 w23 = *(const double2*)&sh.f.sw[par][2];
      const int c0 = kd_idx(w01.x), c1 = kd_idx(w01.y);
      const int c2 = kd_idx(w23.x), c3 = kd_idx(w23.y);
      float4 q0 = sh.f.pp[c0], q1 = sh.f.pp[c1];
      float4 q2 = sh.f.pp[c2], q3 = sh.f.pp[c3];
      const double m01 = fmax(w01.x, w01.y);
      const double m23 = fmax(w23.x, w23.y);
      const double kwin = fmax(m01, m23);
      // keys are unique -> exactly one equality holds per level
      const float4 qa = (w01.x == m01) ? q0 : q1;
      const float4 qb = (w23.x == m23) ? q2 : q3;
      q = (m01 == kwin) ? qa : qb;
      const int cur = kd_idx(kwin);

      if (i >= M_ - 4) {            // capture fps_idx[1020..1023] (block-uniform)
        if      (i == M_ - 4) l0 = cur;
        else if (i == M_ - 3) l1 = cur;
        else if (i == M_ - 2) l2 = cur;
        else                  l3 = cur;
      }
      // publish duty rotates across waves (wave (i&3), lane 0)
      if (tid == ((i & 3) << 6)) {
        __hip_atomic_store(ipub + b * M_ + i, cur + 1, __ATOMIC_RELAXED,
                           __HIP_MEMORY_SCOPE_AGENT);   // datum == flag
        float* o = pos_s + ((size_t)b * M_ + i) * 3;
        o[0] = q.x; o[1] = q.y; o[2] = q.z;
      }
    }

    // ---- self-process the final item (mset 255): pp already staged, no poll ----
    const int w = tid >> 6;
    int ci;
    if      (w == 0) ci = l0;
    else if (w == 1) ci = l1;
    else if (w == 2) ci = l2;
    else             ci = l3;
    process_item(sh, tid, b, 255, ci, x, pos, b1, b2, b3, w1t, w2t, w3t, out);
    return;
  }

  // ================= persistent worker: kNN + MLP per item =================
  const int lane = tid & 63;
  const int w    = tid >> 6;

  for (;;) {
    if (tid == 0) sh_item = atomicAdd(ctr, 1);
    __syncthreads();
    const int it = sh_item;
    if (it >= NITEM) return;
    const int b    = it & 15;
    const int mset = it >> 4;
    const int m    = mset * 4 + w;

    __syncthreads();   // previous item's LDS reads complete before restage
    {
      const float* pb = pos + (size_t)b * N_ * 3;
      for (int i = tid; i < N_; i += 256)
        sh.f.pp[i] = make_float4(pb[3 * i], pb[3 * i + 1], pb[3 * i + 2], 0.0f);
    }
    __syncthreads();   // staging visible to all waves

    // per-wave poll of its own published index (relaxed agent load; the
    // word itself is the ready-flag, so no acquire fence is needed)
    int ci0 = 0;
    if (lane == 0) {
      int v;
      while ((v = __hip_atomic_load(ipub + b * M_ + m, __ATOMIC_RELAXED,
                                    __HIP_MEMORY_SCOPE_AGENT)) == 0)
        __builtin_amdgcn_s_sleep(8);
      ci0 = v - 1;
    }
    const int ci = __shfl(ci0, 0);

    process_item(sh, tid, b, mset, ci, x, pos, b1, b2, b3, w1t, w2t, w3t, out);
    // loop to next item
  }
}

// ---------------------------------------------------------------------------
extern "C" void kernel_launch(void* const* d_in, const int* in_sizes, int n_in,
                              void* d_out, int out_size, void* d_ws, size_t ws_size,
                              hipStream_t stream) {
  const float* x   = (const float*)d_in[0];
  const float* pos = (const float*)d_in[1];
  const float* W1  = (const float*)d_in[2];
  const float* b1  = (const float*)d_in[3];
  const float* W2  = (const float*)d_in[4];
  const float* b2  = (const float*)d_in[5];
  const float* W3  = (const float*)d_in[6];
  const float* b3  = (const float*)d_in[7];

  float* out   = (float*)d_out;
  float* pos_s = out + (size_t)B_ * M_ * 256;

  char* ws = (char*)d_ws;
  int*    ipub = (int*)ws;                        // 65536 B: published idx+1
  int*    ctr  = (int*)(ws + 65536);              // 4 B
  __bf16* w1t  = (__bf16*)(ws + 65792);           // 24576 B
  __bf16* w2t  = (__bf16*)(ws + 90368);           // 32768 B
  __bf16* w3t  = (__bf16*)(ws + 123136);          // 65536 B

  hipMemsetAsync(ws, 0, 65540, stream);           // ipub + ctr
  prep_weights<<<dim3(128), dim3(256), 0, stream>>>(W1, W2, W3, w1t, w2t, w3t);
  fused_kernel<<<dim3(B_ + NWORK), dim3(256), 0, stream>>>(
      pos, x, b1, b2, b3, w1t, w2t, w3t, ipub, ctr, out, pos_s);
}

// Round 19
// 582.261 us; speedup vs baseline: 1.1819x; 1.1819x over previous
//
#include <hip/hip_runtime.h>

// SAModule (PointNet++): FPS -> kNN(32) -> [x||rel] MLP(67->128->128->256) -> max over K.
// B=16, N=4096, C=64, M=1024, K=32.
// R18 = exact revert to R14 (best: 581.3us). R15/R17's post-barrier levers all
// regressed or failed: the FPS exchange path is converged. Final structure:
//  - fused producer/consumer, fence-free ipub publishing (R7),
//  - f64-max argmax keys (R11) + persistent KD pairs (R13),
//  - raw lgkmcnt-only barrier (R10),
//  - CU-exclusive blocks via 84KB LDS padding (R14),
//  - FPS blocks self-process their final mset (R12).

#define B_    16
#define N_    4096
#define M_    1024
#define AST   136
#define NWORK 240
#define NITEM (255 * 16)   // worker items, mset-major: it = mset*16 + b

typedef __bf16 bf16x8 __attribute__((ext_vector_type(8)));
typedef __bf16 bf16x4 __attribute__((ext_vector_type(4)));
typedef float  f32x4  __attribute__((ext_vector_type(4)));
typedef float  f32x2  __attribute__((ext_vector_type(2)));

// ---------------------------------------------------------------------------
// Weight prep: transpose + cast to bf16, pad W1 K-dim 67->96 with zeros.
// ---------------------------------------------------------------------------
__global__ __launch_bounds__(256) void prep_weights(
    const float* __restrict__ W1, const float* __restrict__ W2,
    const float* __restrict__ W3,
    __bf16* __restrict__ w1t, __bf16* __restrict__ w2t, __bf16* __restrict__ w3t) {
  const int t = blockIdx.x * 256 + threadIdx.x;   // 0..32767
  if (t < 128 * 96) {
    const int n = t / 96, k = t % 96;
    w1t[t] = (k < 67) ? (__bf16)W1[k * 128 + n] : (__bf16)0.0f;
  }
  if (t < 128 * 128) {
    const int n = t >> 7, k = t & 127;
    w2t[t] = (__bf16)W2[k * 128 + n];
  }
  {
    const int n = t >> 7, k = t & 127;   // t < 256*128 always
    w3t[t] = (__bf16)W3[k * 256 + n];
  }
}

// ---------------------------------------------------------------------------
__device__ __forceinline__ f32x2 pk_sub(f32x2 a, f32x2 b) {
  f32x2 d;
  asm("v_pk_add_f32 %0, %1, %2 neg_lo:[0,1] neg_hi:[0,1]" : "=v"(d) : "v"(a), "v"(b));
  return d;
}
__device__ __forceinline__ f32x2 pk_mul(f32x2 a, f32x2 b) {
  f32x2 d;
  asm("v_pk_mul_f32 %0, %1, %2" : "=v"(d) : "v"(a), "v"(b));
  return d;
}
__device__ __forceinline__ f32x2 pk_add(f32x2 a, f32x2 b) {
  f32x2 d;
  asm("v_pk_add_f32 %0, %1, %2" : "=v"(d) : "v"(a), "v"(b));
  return d;
}

// argmax key as positive f64: hi = f32 bits of D (>=0, < 0x7FF00000), lo = ~idx.
// IEEE f64 ordering == u64 bit ordering for these patterns.
__device__ __forceinline__ double mk_key(float d, unsigned lo) {
  unsigned long long k = ((unsigned long long)__float_as_uint(d) << 32) | lo;
  return __builtin_bit_cast(double, k);
}
// hi-half (the f32 distance) of a key; lo-half is a per-slot constant.
__device__ __forceinline__ float kd_hi(double k) {
  return __int_as_float((int)(__builtin_bit_cast(unsigned long long, k) >> 32));
}
__device__ __forceinline__ double kd_set_hi(double k, float h) {
  unsigned long long u = __builtin_bit_cast(unsigned long long, k);
  u = (u & 0xFFFFFFFFull) | ((unsigned long long)__float_as_uint(h) << 32);
  return __builtin_bit_cast(double, u);
}

template <int CTRL>
__device__ __forceinline__ double dpp_max_f64(double v) {
  unsigned long long k = __builtin_bit_cast(unsigned long long, v);
  unsigned lo = (unsigned)__builtin_amdgcn_update_dpp(0, (int)(unsigned)k,         CTRL, 0xF, 0xF, true);
  unsigned hi = (unsigned)__builtin_amdgcn_update_dpp(0, (int)(unsigned)(k >> 32), CTRL, 0xF, 0xF, true);
  double p = __builtin_bit_cast(double, ((unsigned long long)hi << 32) | lo);
  return fmax(v, p);   // 0-filled lanes give +0.0, which always loses (keys > 0)
}

union ShU {
  struct { float4 pp[N_]; unsigned long long sw[2][4]; } f;   // fps / knn view
  struct { __bf16 A[128 * AST]; __bf16 Bv[128 * AST]; } g;    // mlp view
  char force_cu_exclusive[84 * 1024];   // 2x84KB > 160KB -> 1 block/CU, HW-guaranteed
};

// ---------------------------------------------------------------------------
// kNN + gather + MLP + maxpool for one (b, mset) item. Requires sh.f.pp to
// hold cloud b as float4 and ci = this wave's centroid point index.
// ---------------------------------------------------------------------------
__device__ __forceinline__ void process_item(
    ShU& sh, int tid, int b, int mset, int ci,
    const float* __restrict__ x, const float* __restrict__ pos,
    const float* __restrict__ b1, const float* __restrict__ b2,
    const float* __restrict__ b3,
    const __bf16* __restrict__ w1t, const __bf16* __restrict__ w2t,
    const __bf16* __restrict__ w3t, float* __restrict__ out) {
  const int w    = tid >> 6;
  const int lane = tid & 63;
  const float4 c = sh.f.pp[ci];

  // ---- kNN pass A: distances + lane-min key ----
  float d2v[64];
  unsigned long long kmin = ~0ull;
#pragma unroll
  for (int t = 0; t < 64; t++) {
    const int j = t * 64 + lane;
    const float4 p = sh.f.pp[j];
    float dx = __fsub_rn(p.x, c.x);
    float dy = __fsub_rn(p.y, c.y);
    float dz = __fsub_rn(p.z, c.z);
    float d  = __fadd_rn(__fadd_rn(__fmul_rn(dx, dx), __fmul_rn(dy, dy)),
                         __fmul_rn(dz, dz));
    d2v[t] = d;
    const unsigned long long k64 =
        ((unsigned long long)__float_as_uint(d) << 32) | (unsigned int)j;
    if (k64 < kmin) kmin = k64;
  }

  // ---- bitonic sort of lane-min keys; seed top-32; threshold T0 ----
  unsigned long long sk = kmin;
#pragma unroll
  for (int size = 2; size <= 64; size <<= 1) {
#pragma unroll
    for (int stride = size >> 1; stride > 0; stride >>= 1) {
      const unsigned long long other = __shfl_xor(sk, stride);
      const bool up      = ((lane & size) == 0);
      const bool lowhalf = ((lane & stride) == 0);
      const bool takeMin = (up == lowhalf);
      const bool swp     = takeMin ? (other < sk) : (other > sk);
      if (swp) sk = other;
    }
  }
  const unsigned long long T0 = __shfl(sk, 31);
  const bool seeded = (kmin <= T0);

  unsigned long long rkey = (lane < 32) ? sk : ~0ull;
  unsigned long long wk   = T0;

  // ---- pass B: scan, skipping seeded keys ----
#pragma unroll
  for (int t = 0; t < 64; t++) {
    const int j = t * 64 + lane;
    const unsigned long long k64 =
        ((unsigned long long)__float_as_uint(d2v[t]) << 32) | (unsigned int)j;
    const bool skip = seeded && (k64 == kmin);
    unsigned long long mask = __ballot((k64 < wk) && !skip);
    if (mask) {
      while (mask) {
        const int src = __ffsll((unsigned long long)mask) - 1;
        mask &= mask - 1;
        const unsigned long long cand = __shfl(k64, src);
        const int pos_i = (int)__popcll(__ballot(rkey < cand));  // >=32 -> no-op
        const unsigned long long sh_ = __shfl_up(rkey, 1);
        if (lane < 32) {
          if (lane == pos_i)      rkey = cand;
          else if (lane > pos_i)  rkey = sh_;
        }
      }
      wk = __shfl(rkey, 31);
    }
  }
  const int njl = (int)(rkey & 0xFFFFull);   // valid in lanes 0..31
  __syncthreads();   // all pp reads done before mlp buffers alias it

  // ---- gather: wave w fills rows [32w,32w+32) for its centroid ----
  {
    const int rl   = lane >> 1;
    const int half = lane & 1;
    const int r    = w * 32 + rl;
    const int nj   = __shfl(njl, rl);
    const float4* xr = (const float4*)(x + ((size_t)(b * N_ + nj)) * 64 + half * 32);
    __bf16* dst = &sh.g.A[r * AST + half * 32];
#pragma unroll
    for (int t = 0; t < 8; t++) {
      float4 v = xr[t];
      bf16x4 u;
      u[0] = (__bf16)v.x; u[1] = (__bf16)v.y; u[2] = (__bf16)v.z; u[3] = (__bf16)v.w;
      *(bf16x4*)(dst + t * 4) = u;
    }
    bf16x8 z;
#pragma unroll
    for (int q2 = 0; q2 < 8; q2++) z[q2] = (__bf16)0.0f;
    if (half == 0) {
      const float* pj = pos + ((size_t)(b * N_ + nj)) * 3;
      bf16x8 u = z;
      u[0] = (__bf16)(pj[0] - c.x);
      u[1] = (__bf16)(pj[1] - c.y);
      u[2] = (__bf16)(pj[2] - c.z);
      *(bf16x8*)&sh.g.A[r * AST + 64] = u;
      *(bf16x8*)&sh.g.A[r * AST + 72] = z;
    } else {
      *(bf16x8*)&sh.g.A[r * AST + 80] = z;
      *(bf16x8*)&sh.g.A[r * AST + 88] = z;
    }
  }
  __syncthreads();

  const int lrow = lane & 15;
  const int lk8  = (lane >> 4) << 3;
  const int orow = (lane >> 4) << 2;

  // ---- L1: msg(96) @ W1 -> relu -> Bv. Wave w: cols [32w,32w+32) ----
  {
    f32x4 acc[8][2];
#pragma unroll
    for (int n = 0; n < 2; n++) {
      const float bv = b1[(2 * w + n) * 16 + lrow];
      f32x4 a = {bv, bv, bv, bv};
#pragma unroll
      for (int rt = 0; rt < 8; rt++) acc[rt][n] = a;
    }
#pragma unroll
    for (int s = 0; s < 3; s++) {
      bf16x8 a[8];
#pragma unroll
      for (int rt = 0; rt < 8; rt++)
        a[rt] = *(const bf16x8*)&sh.g.A[(rt * 16 + lrow) * AST + s * 32 + lk8];
#pragma unroll
      for (int n = 0; n < 2; n++) {
        bf16x8 bb = *(const bf16x8*)&w1t[((2 * w + n) * 16 + lrow) * 96 + s * 32 + lk8];
#pragma unroll
        for (int rt = 0; rt < 8; rt++)
          acc[rt][n] = __builtin_amdgcn_mfma_f32_16x16x32_bf16(a[rt], bb, acc[rt][n], 0, 0, 0);
      }
    }
    __syncthreads();
#pragma unroll
    for (int n = 0; n < 2; n++)
#pragma unroll
      for (int rt = 0; rt < 8; rt++)
#pragma unroll
        for (int j = 0; j < 4; j++)
          sh.g.Bv[(rt * 16 + orow + j) * AST + (2 * w + n) * 16 + lrow] =
              (__bf16)fmaxf(acc[rt][n][j], 0.0f);
  }
  __syncthreads();

  // ---- L2: Bv(128) @ W2 -> relu -> A ----
  {
    f32x4 acc[8][2];
#pragma unroll
    for (int n = 0; n < 2; n++) {
      const float bv = b2[(2 * w + n) * 16 + lrow];
      f32x4 a = {bv, bv, bv, bv};
#pragma unroll
      for (int rt = 0; rt < 8; rt++) acc[rt][n] = a;
    }
#pragma unroll
    for (int s = 0; s < 4; s++) {
      bf16x8 a[8];
#pragma unroll
      for (int rt = 0; rt < 8; rt++)
        a[rt] = *(const bf16x8*)&sh.g.Bv[(rt * 16 + lrow) * AST + s * 32 + lk8];
#pragma unroll
      for (int n = 0; n < 2; n++) {
        bf16x8 bb = *(const bf16x8*)&w2t[((2 * w + n) * 16 + lrow) * 128 + s * 32 + lk8];
#pragma unroll
        for (int rt = 0; rt < 8; rt++)
          acc[rt][n] = __builtin_amdgcn_mfma_f32_16x16x32_bf16(a[rt], bb, acc[rt][n], 0, 0, 0);
      }
    }
    __syncthreads();
#pragma unroll
    for (int n = 0; n < 2; n++)
#pragma unroll
      for (int rt = 0; rt < 8; rt++)
#pragma unroll
        for (int j = 0; j < 4; j++)
          sh.g.A[(rt * 16 + orow + j) * AST + (2 * w + n) * 16 + lrow] =
              (__bf16)fmaxf(acc[rt][n][j], 0.0f);
  }
  __syncthreads();

  // ---- L3 + maxpool. Wave w: cols [64w,64w+64) in two passes ----
#pragma unroll
  for (int np = 0; np < 2; np++) {
    f32x4 acc[8][2];
#pragma unroll
    for (int n = 0; n < 2; n++) {
      const float bv = b3[(4 * w + 2 * np + n) * 16 + lrow];
      f32x4 a = {bv, bv, bv, bv};
#pragma unroll
      for (int rt = 0; rt < 8; rt++) acc[rt][n] = a;
    }
#pragma unroll
    for (int s = 0; s < 4; s++) {
      bf16x8 a[8];
#pragma unroll
      for (int rt = 0; rt < 8; rt++)
        a[rt] = *(const bf16x8*)&sh.g.A[(rt * 16 + lrow) * AST + s * 32 + lk8];
#pragma unroll
      for (int n = 0; n < 2; n++) {
        bf16x8 bb = *(const bf16x8*)&w3t[((4 * w + 2 * np + n) * 16 + lrow) * 128 + s * 32 + lk8];
#pragma unroll
        for (int rt = 0; rt < 8; rt++)
          acc[rt][n] = __builtin_amdgcn_mfma_f32_16x16x32_bf16(a[rt], bb, acc[rt][n], 0, 0, 0);
      }
    }
#pragma unroll
    for (int ccc = 0; ccc < 4; ccc++) {
#pragma unroll
      for (int n = 0; n < 2; n++) {
        f32x4 a0 = acc[2 * ccc][n], a1 = acc[2 * ccc + 1][n];
        float v = fmaxf(fmaxf(fmaxf(a0[0], a0[1]), fmaxf(a0[2], a0[3])),
                        fmaxf(fmaxf(a1[0], a1[1]), fmaxf(a1[2], a1[3])));
        v = fmaxf(v, __shfl_xor(v, 16));
        v = fmaxf(v, __shfl_xor(v, 32));
        v = fmaxf(v, 0.0f);
        if (lane < 16)
          out[((size_t)(b * M_ + mset * 4 + ccc)) * 256 + (4 * w + 2 * np + n) * 16 + lane] = v;
      }
    }
  }
}

// ---------------------------------------------------------------------------
__global__ __launch_bounds__(256) void fused_kernel(
    const float* __restrict__ pos, const float* __restrict__ x,
    const float* __restrict__ b1, const float* __restrict__ b2,
    const float* __restrict__ b3,
    const __bf16* __restrict__ w1t, const __bf16* __restrict__ w2t,
    const __bf16* __restrict__ w3t,
    int* __restrict__ ipub, int* __restrict__ ctr,
    float* __restrict__ out, float* __restrict__ pos_s) {
  __shared__ alignas(16) ShU sh;
  __shared__ int sh_item;
  const int tid = threadIdx.x;

  if (blockIdx.x < B_) {
    // ============ FPS producer (R13 body, CU-exclusive by LDS size) ==========
    __builtin_amdgcn_s_setprio(3);
    const int b = blockIdx.x;
    const float* pb = pos + (size_t)b * N_ * 3;
    for (int i = tid; i < N_; i += 256)
      sh.f.pp[i] = make_float4(pb[3 * i], pb[3 * i + 1], pb[3 * i + 2], 0.0f);
    __syncthreads();

    f32x2 X2[8], Y2[8], Z2[8];
    double KD[16];   // persistent keys: lo32 = ~idx (never changes), hi32 = f32bits(D)
    const unsigned ntid = ~(unsigned)tid;
#pragma unroll
    for (int j = 0; j < 8; j++) {
      float4 p0 = sh.f.pp[tid + ((2 * j) << 8)];
      float4 p1 = sh.f.pp[tid + ((2 * j + 1) << 8)];
      X2[j][0] = p0.x; X2[j][1] = p1.x;
      Y2[j][0] = p0.y; Y2[j][1] = p1.y;
      Z2[j][0] = p0.z; Z2[j][1] = p1.z;
      KD[2 * j]     = mk_key(1e30f, ntid - (unsigned)((2 * j) << 8));
      KD[2 * j + 1] = mk_key(1e30f, ntid - (unsigned)((2 * j + 1) << 8));
    }

    float4 q = sh.f.pp[0];
    if (tid == 0) {
      __hip_atomic_store(ipub + b * M_, 1, __ATOMIC_RELAXED,
                         __HIP_MEMORY_SCOPE_AGENT);   // idx 0, published as 0+1
      float* o = pos_s + (size_t)b * M_ * 3;
      o[0] = q.x; o[1] = q.y; o[2] = q.z;
    }

    int l0 = 0, l1 = 0, l2 = 0, l3 = 0;   // fps_idx[1020..1023]
    for (int i = 1; i < M_; i++) {
      f32x2 qx; qx[0] = q.x; qx[1] = q.x;
      f32x2 qy; qy[0] = q.y; qy[1] = q.y;
      f32x2 qz; qz[0] = q.z; qz[1] = q.z;
#pragma unroll
      for (int j = 0; j < 8; j++) {
        f32x2 dx = pk_sub(X2[j], qx);
        f32x2 dy = pk_sub(Y2[j], qy);
        f32x2 dz = pk_sub(Z2[j], qz);
        f32x2 t0 = pk_mul(dx, dx);
        f32x2 t1 = pk_mul(dy, dy);
        f32x2 s  = pk_add(t0, t1);
        f32x2 t2 = pk_mul(dz, dz);
        f32x2 d2 = pk_add(s, t2);
        // in-place hi-half update: v_min_f32 on the pair's hi reg, no packing
        KD[2 * j]     = kd_set_hi(KD[2 * j],     fminf(kd_hi(KD[2 * j]),     d2[0]));
        KD[2 * j + 1] = kd_set_hi(KD[2 * j + 1], fminf(kd_hi(KD[2 * j + 1]), d2[1]));
      }
      // tree reduce, level 1 non-destructive (KD persists across iterations)
      double t[8];
#pragma unroll
      for (int k = 0; k < 8; k++) t[k] = fmax(KD[k], KD[k + 8]);
#pragma unroll
      for (int s = 4; s > 0; s >>= 1)
#pragma unroll
        for (int k = 0; k < s; k++) t[k] = fmax(t[k], t[k + s]);
      double kk = t[0];

      // full-wave VALU-pipe reduce: lane 63 ends with the wave max
      kk = dpp_max_f64<0xB1>(kk);    // quad_perm xor1
      kk = dpp_max_f64<0x4E>(kk);    // quad_perm xor2
      kk = dpp_max_f64<0x141>(kk);   // row_half_mirror (xor4)
      kk = dpp_max_f64<0x140>(kk);   // row_mirror (xor8)
      kk = dpp_max_f64<0x142>(kk);   // row_bcast15
      kk = dpp_max_f64<0x143>(kk);   // row_bcast31

      const int par = i & 1;
      if ((tid & 63) == 63)
        sh.f.sw[par][tid >> 6] = __builtin_bit_cast(unsigned long long, kk);
      // LDS-only fence + raw barrier (global stores stay fire-and-forget)
      asm volatile("s_waitcnt lgkmcnt(0)" ::: "memory");
      __builtin_amdgcn_s_barrier();

      // f64-max select: 3 fmax + single dependent pp read (no cndmask chain)
      const double2 w01 = *(const double2*)&sh.f.sw[par][0];
      const double2 w23 = *(const double2*)&sh.f.sw[par][2];
      const double kwin = fmax(fmax(w01.x, w01.y), fmax(w23.x, w23.y));
      const unsigned long long kwb = __builtin_bit_cast(unsigned long long, kwin);
      const int cur = (int)(~(unsigned)kwb);
      q = sh.f.pp[cur];

      if (i >= M_ - 4) {            // capture fps_idx[1020..1023] (block-uniform)
        if      (i == M_ - 4) l0 = cur;
        else if (i == M_ - 3) l1 = cur;
        else if (i == M_ - 2) l2 = cur;
        else                  l3 = cur;
      }
      if (tid == 0) {
        __hip_atomic_store(ipub + b * M_ + i, cur + 1, __ATOMIC_RELAXED,
                           __HIP_MEMORY_SCOPE_AGENT);   // datum == flag
        float* o = pos_s + ((size_t)b * M_ + i) * 3;
        o[0] = q.x; o[1] = q.y; o[2] = q.z;
      }
    }

    // ---- self-process the final item (mset 255): pp already staged, no poll ----
    const int w = tid >> 6;
    int ci;
    if      (w == 0) ci = l0;
    else if (w == 1) ci = l1;
    else if (w == 2) ci = l2;
    else             ci = l3;
    process_item(sh, tid, b, 255, ci, x, pos, b1, b2, b3, w1t, w2t, w3t, out);
    return;
  }

  // ================= persistent worker: kNN + MLP per item =================
  const int lane = tid & 63;
  const int w    = tid >> 6;

  for (;;) {
    if (tid == 0) sh_item = atomicAdd(ctr, 1);
    __syncthreads();
    const int it = sh_item;
    if (it >= NITEM) return;
    const int b    = it & 15;
    const int mset = it >> 4;
    const int m    = mset * 4 + w;

    __syncthreads();   // previous item's LDS reads complete before restage
    {
      const float* pb = pos + (size_t)b * N_ * 3;
      for (int i = tid; i < N_; i += 256)
        sh.f.pp[i] = make_float4(pb[3 * i], pb[3 * i + 1], pb[3 * i + 2], 0.0f);
    }
    __syncthreads();   // staging visible to all waves

    // per-wave poll of its own published index (relaxed agent load; the
    // word itself is the ready-flag, so no acquire fence is needed)
    int ci0 = 0;
    if (lane == 0) {
      int v;
      while ((v = __hip_atomic_load(ipub + b * M_ + m, __ATOMIC_RELAXED,
                                    __HIP_MEMORY_SCOPE_AGENT)) == 0)
        __builtin_amdgcn_s_sleep(8);
      ci0 = v - 1;
    }
    const int ci = __shfl(ci0, 0);

    process_item(sh, tid, b, mset, ci, x, pos, b1, b2, b3, w1t, w2t, w3t, out);
    // loop to next item
  }
}

// ---------------------------------------------------------------------------
extern "C" void kernel_launch(void* const* d_in, const int* in_sizes, int n_in,
                              void* d_out, int out_size, void* d_ws, size_t ws_size,
                              hipStream_t stream) {
  const float* x   = (const float*)d_in[0];
  const float* pos = (const float*)d_in[1];
  const float* W1  = (const float*)d_in[2];
  const float* b1  = (const float*)d_in[3];
  const float* W2  = (const float*)d_in[4];
  const float* b2  = (const float*)d_in[5];
  const float* W3  = (const float*)d_in[6];
  const float* b3  = (const float*)d_in[7];

  float* out   = (float*)d_out;
  float* pos_s = out + (size_t)B_ * M_ * 256;

  char* ws = (char*)d_ws;
  int*    ipub = (int*)ws;                        // 65536 B: published idx+1
  int*    ctr  = (int*)(ws + 65536);              // 4 B
  __bf16* w1t  = (__bf16*)(ws + 65792);           // 24576 B
  __bf16* w2t  = (__bf16*)(ws + 90368);           // 32768 B
  __bf16* w3t  = (__bf16*)(ws + 123136);          // 65536 B

  hipMemsetAsync(ws, 0, 65540, stream);           // ipub + ctr
  prep_weights<<<dim3(128), dim3(256), 0, stream>>>(W1, W2, W3, w1t, w2t, w3t);
  fused_kernel<<<dim3(B_ + NWORK), dim3(256), 0, stream>>>(
      pos, x, b1, b2, b3, w1t, w2t, w3t, ipub, ctr, out, pos_s);
}